// Round 2
// baseline (232.878 us; speedup 1.0000x reference)
//
#include <hip/hip_runtime.h>
#include <hip/hip_bf16.h>

typedef __bf16 bf16_t;
typedef _Float16 f16_t;
typedef bf16_t bf16x8 __attribute__((ext_vector_type(8)));
typedef f16_t  f16x8  __attribute__((ext_vector_type(8)));
typedef f16_t  f16x4  __attribute__((ext_vector_type(4)));
typedef float  floatx4 __attribute__((ext_vector_type(4)));
typedef float  floatx16 __attribute__((ext_vector_type(16)));
typedef bf16x8 bf16x8u __attribute__((aligned(8)));
typedef f16x8  f16x8u  __attribute__((aligned(8)));

#define DEV static __device__ __forceinline__

DEV floatx4 mfma16_bf16(bf16x8 a, bf16x8 b, floatx4 c) {
  return __builtin_amdgcn_mfma_f32_16x16x32_bf16(a, b, c, 0, 0, 0);
}
DEV floatx4 mfma16_f16(f16x8 a, f16x8 b, floatx4 c) {
  return __builtin_amdgcn_mfma_f32_16x16x32_f16(a, b, c, 0, 0, 0);
}
DEV floatx16 mfma32_bf16(bf16x8 a, bf16x8 b, floatx16 c) {
  return __builtin_amdgcn_mfma_f32_32x32x16_bf16(a, b, c, 0, 0, 0);
}
DEV floatx16 mfma32x8_f16(f16x4 a, f16x4 b, floatx16 c) {
  return __builtin_amdgcn_mfma_f32_32x32x8f16(a, b, c, 0, 0, 0);
}
DEV void async_ld16(void* lds, const void* g) {
  __builtin_amdgcn_global_load_lds(
      (const __attribute__((address_space(1))) unsigned int*)g,
      (__attribute__((address_space(3))) unsigned int*)lds, 16, 0, 0);
}
DEV float fast_exp2(float x) {  // v_exp_f32 = 2^x, no libm slow path
  float r;
  asm("v_exp_f32 %0, %1" : "=v"(r) : "v"(x));
  return r;
}

// ---------------------------------------------------------------------------
// Prep: LDS-transposed weight prep (coalesced stores). K weights -> bf16 hi/lo
// [n][k] (+lo at +16384 elems); V weights -> f16 [n][k]. Plus t2 gather.
// ---------------------------------------------------------------------------
__global__ void prep_kernel(const float* __restrict__ Wk1, const float* __restrict__ Wk2,
                            const float* __restrict__ Wv1, const float* __restrict__ Wv2,
                            const float* __restrict__ X,
                            bf16_t* __restrict__ W1p, bf16_t* __restrict__ W2p,
                            f16_t* __restrict__ W3f, f16_t* __restrict__ W4f,
                            float* __restrict__ t2pre) {
  int b = blockIdx.x;
  if (b < 16) {
    int m = b >> 2, p = b & 3;   // weight m, k-quarter p (rows k in [32p,32p+32))
    const float* src = m == 0 ? Wk1 : m == 1 ? Wk2 : m == 2 ? Wv1 : Wv2;
    __shared__ float tile[32][129];
    for (int u = 0; u < 4; ++u) {
      int idx = threadIdx.x + u * 256;        // 1024 float4 units
      int k = idx >> 5, n4 = (idx & 31) << 2;
      float4 v = *(const float4*)(src + (size_t)(p * 32 + k) * 128 + n4);
      tile[k][n4 + 0] = v.x; tile[k][n4 + 1] = v.y;
      tile[k][n4 + 2] = v.z; tile[k][n4 + 3] = v.w;
    }
    __syncthreads();
    if (m < 2) {
      bf16_t* dst = m ? W2p : W1p;
      for (int u = 0; u < 2; ++u) {
        int idx = threadIdx.x + u * 256;      // 512 units: n, k-chunk of 8
        int n = idx >> 2, kc = idx & 3;
        bf16x8 hi, lo;
        for (int j = 0; j < 8; ++j) {
          float v = tile[kc * 8 + j][n];
          bf16_t hh = (bf16_t)v;
          hi[j] = hh;
          lo[j] = (bf16_t)(v - (float)hh);
        }
        *(bf16x8*)(dst + n * 128 + p * 32 + kc * 8) = hi;
        *(bf16x8*)(dst + 16384 + n * 128 + p * 32 + kc * 8) = lo;
      }
    } else {
      f16_t* dst = (m == 3) ? W4f : W3f;
      for (int u = 0; u < 2; ++u) {
        int idx = threadIdx.x + u * 256;
        int n = idx >> 2, kc = idx & 3;
        f16x8 w;
        for (int j = 0; j < 8; ++j) w[j] = (f16_t)tile[kc * 8 + j][n];
        *(f16x8*)(dst + n * 128 + p * 32 + kc * 8) = w;
      }
    }
  } else {
    int i = (b - 16) * 256 + threadIdx.x;     // n*1024 + l
    t2pre[i] = X[((size_t)(i >> 10) * 8192 + (i & 1023)) * 128 + 127];
  }
}

// ---------------------------------------------------------------------------
// MLP-K: split-bf16, 64 rows/block, dbuf weight staging (8 phases).
// ---------------------------------------------------------------------------
__global__ __launch_bounds__(256) void mlp_k_kernel(
    const float* __restrict__ X, const float* __restrict__ b1,
    const float* __restrict__ b2, const bf16_t* __restrict__ W1p,
    const bf16_t* __restrict__ W2p, bf16_t* __restrict__ Khi,
    bf16_t* __restrict__ Klo) {
  __shared__ __align__(16) char sXbuf[2 * 16896];
  __shared__ __align__(16) bf16_t sW[2][256 * 40];
  bf16_t* sXh = (bf16_t*)sXbuf;
  bf16_t* sXl = sXh + 64 * 132;

  const int tid = threadIdx.x, lane = tid & 63, wave = tid >> 6;
  const int q = lane >> 4, c15 = lane & 15;
  const size_t rowBase = (size_t)blockIdx.x * 64;

  int goff[5];
  for (int a = 0; a < 5; ++a) {
    int o = (wave + 4 * a) * 1024 + lane * 16;
    int row = o / 80, rem = o % 80;
    goff[a] = row * 256 + (rem < 64 ? rem : 0);
  }
  auto issueW = [&](int buf, int ph) {
    const bf16_t* Wp = (ph < 4) ? W1p : W2p;
    const char* base = (const char*)Wp + (ph & 3) * 64;
    for (int a = 0; a < 5; ++a)
      async_ld16((char*)sW[buf] + (wave + 4 * a) * 1024 + lane * 16, base + goff[a]);
  };

  issueW(0, 0);    // prefetch W phase 0 under X conversion

  float b1v[8], b2v[8];
  for (int nt = 0; nt < 8; ++nt) { b1v[nt] = b1[nt * 16 + c15]; b2v[nt] = b2[nt * 16 + c15]; }

  for (int u = 0; u < 8; ++u) {
    int idx = tid + u * 256;
    int r = idx >> 5, c4 = (idx & 31) << 2;
    float4 v = *(const float4*)(X + (rowBase + r) * 128 + c4);
    int o = r * 132 + c4;
    float vv[4] = {v.x, v.y, v.z, v.w};
    for (int i = 0; i < 4; ++i) {
      bf16_t h = (bf16_t)vv[i];
      sXh[o + i] = h;
      sXl[o + i] = (bf16_t)(vv[i] - (float)h);
    }
  }

  floatx4 acc1[8], acc2[8];
  for (int i = 0; i < 8; ++i) { acc1[i] = {}; acc2[i] = {}; }

  __syncthreads();
#pragma unroll
  for (int ph = 0; ph < 8; ++ph) {
    if (ph < 7) issueW((ph + 1) & 1, ph + 1);
    const bf16_t* wb = sW[ph & 1];
    const int kq = ph & 3;
    floatx4* acc = (ph < 4) ? acc1 : acc2;
    const int ao = (wave * 16 + c15) * 132 + kq * 32 + q * 8;
    bf16x8 ah = *(const bf16x8u*)(sXh + ao);
    bf16x8 al = *(const bf16x8u*)(sXl + ao);
    for (int nt = 0; nt < 8; ++nt) {
      const int bo = (nt * 16 + c15) * 40 + q * 8;
      bf16x8 bh = *(const bf16x8*)(wb + bo);
      bf16x8 bl = *(const bf16x8*)(wb + 128 * 40 + bo);
      acc[nt] = mfma16_bf16(ah, bh, acc[nt]);
      acc[nt] = mfma16_bf16(ah, bl, acc[nt]);
      acc[nt] = mfma16_bf16(al, bh, acc[nt]);
    }
    if (ph == 3) {
      for (int nt = 0; nt < 8; ++nt)
        for (int r = 0; r < 4; ++r) {
          float h = fmaxf(acc1[nt][r] + b1v[nt], 0.f);
          bf16_t hh = (bf16_t)h;
          int o = (wave * 16 + q * 4 + r) * 132 + nt * 16 + c15;
          sXh[o] = hh;
          sXl[o] = (bf16_t)(h - (float)hh);
        }
    }
    __syncthreads();
  }

  for (int nt = 0; nt < 8; ++nt)
    for (int r = 0; r < 4; ++r) {
      float kv = acc2[nt][r] + b2v[nt];
      bf16_t kh = (bf16_t)kv;
      int o = (wave * 16 + q * 4 + r) * 132 + nt * 16 + c15;
      sXh[o] = kh;
      sXl[o] = (bf16_t)(kv - (float)kh);
    }
  __syncthreads();
  for (int u = 0; u < 4; ++u) {
    int idx = tid + u * 256;
    int r = idx >> 4, c8 = (idx & 15) << 3;
    bf16x8 vh = *(const bf16x8u*)(sXh + r * 132 + c8);
    bf16x8 vl = *(const bf16x8u*)(sXl + r * 132 + c8);
    *(bf16x8*)(Khi + (rowBase + r) * 128 + c8) = vh;
    *(bf16x8*)(Klo + (rowBase + r) * 128 + c8) = vl;
  }
}

// ---------------------------------------------------------------------------
// MLP-V: pure f16 (R2-proven numerics), dbuf phases; emits V^T (f16).
// ---------------------------------------------------------------------------
__global__ __launch_bounds__(256) void mlp_v_kernel(
    const float* __restrict__ X, const float* __restrict__ b1,
    const float* __restrict__ b2, const f16_t* __restrict__ W1f,
    const f16_t* __restrict__ W2f, f16_t* __restrict__ Vt) {
  __shared__ __align__(16) f16_t sXf[64 * 136];    // X/H; later V^T [128][68]
  __shared__ __align__(16) f16_t sW[2][128 * 40];

  const int tid = threadIdx.x, lane = tid & 63, wave = tid >> 6;
  const int q = lane >> 4, c15 = lane & 15;
  const size_t rowBase = (size_t)blockIdx.x * 64;

  int goff[3];
  for (int a = 0; a < 3; ++a) {
    int o = (wave + 4 * a) * 1024 + lane * 16;
    int row = o / 80, rem = o % 80;
    goff[a] = row * 256 + (rem < 64 ? rem : 0);
  }
  auto issueV = [&](int buf, int ph) {
    const f16_t* Wp = (ph < 4) ? W1f : W2f;
    const char* base = (const char*)Wp + (ph & 3) * 64;
    for (int a = 0; a < 3; ++a) {
      int j = wave + 4 * a;
      if (j < 10) async_ld16((char*)sW[buf] + j * 1024 + lane * 16, base + goff[a]);
    }
  };

  issueV(0, 0);

  float b1v[8], bvv[2][4];
  for (int nt = 0; nt < 8; ++nt) b1v[nt] = b1[nt * 16 + c15];
  for (int mt = 0; mt < 2; ++mt)
    for (int r = 0; r < 4; ++r)
      bvv[mt][r] = b2[(wave * 2 + mt) * 16 + q * 4 + r];

  for (int u = 0; u < 8; ++u) {
    int idx = tid + u * 256;
    int r = idx >> 5, c4 = (idx & 31) << 2;
    float4 v = *(const float4*)(X + (rowBase + r) * 128 + c4);
    int o = r * 136 + c4;
    sXf[o + 0] = (f16_t)v.x; sXf[o + 1] = (f16_t)v.y;
    sXf[o + 2] = (f16_t)v.z; sXf[o + 3] = (f16_t)v.w;
  }

  floatx4 acc1[8], acc2[2][4];
  for (int i = 0; i < 8; ++i) acc1[i] = {};
  for (int i = 0; i < 2; ++i) for (int j = 0; j < 4; ++j) acc2[i][j] = {};

  __syncthreads();
#pragma unroll
  for (int ph = 0; ph < 8; ++ph) {
    if (ph < 7) issueV((ph + 1) & 1, ph + 1);
    const f16_t* wb = sW[ph & 1];
    const int kq = ph & 3;
    if (ph < 4) {
      f16x8 a = *(const f16x8u*)(sXf + (wave * 16 + c15) * 136 + kq * 32 + q * 8);
      for (int nt = 0; nt < 8; ++nt) {
        f16x8 bb = *(const f16x8*)(wb + (nt * 16 + c15) * 40 + q * 8);
        acc1[nt] = mfma16_f16(a, bb, acc1[nt]);
      }
      if (ph == 3) {
        for (int nt = 0; nt < 8; ++nt)
          for (int r = 0; r < 4; ++r)
            sXf[(wave * 16 + q * 4 + r) * 136 + nt * 16 + c15] =
                (f16_t)fmaxf(acc1[nt][r] + b1v[nt], 0.f);
      }
    } else {
      f16x8 aw0 = *(const f16x8*)(wb + ((wave * 2 + 0) * 16 + c15) * 40 + q * 8);
      f16x8 aw1 = *(const f16x8*)(wb + ((wave * 2 + 1) * 16 + c15) * 40 + q * 8);
      for (int nt = 0; nt < 4; ++nt) {
        f16x8 bh = *(const f16x8u*)(sXf + (nt * 16 + c15) * 136 + kq * 32 + q * 8);
        acc2[0][nt] = mfma16_f16(aw0, bh, acc2[0][nt]);
        acc2[1][nt] = mfma16_f16(aw1, bh, acc2[1][nt]);
      }
    }
    __syncthreads();
  }

  f16_t* sVT = sXf;   // [128][68] f16
  for (int mt = 0; mt < 2; ++mt)
    for (int nt = 0; nt < 4; ++nt)
      for (int r = 0; r < 4; ++r) {
        int c = (wave * 2 + mt) * 16 + q * 4 + r;
        sVT[c * 68 + nt * 16 + c15] = (f16_t)(acc2[mt][nt][r] + bvv[mt][r]);
      }
  __syncthreads();
  const int nh = (int)(rowBase >> 10);
  const int lB = (int)(rowBase & 1023);
  for (int u = 0; u < 4; ++u) {
    int idx = tid + u * 256;
    int c = idx >> 3, l8 = (idx & 7) << 3;
    *(f16x8*)(Vt + ((size_t)nh * 128 + c) * 1024 + lB + l8) =
        *(const f16x8u*)(sVT + c * 68 + l8);
  }
}

// ---------------------------------------------------------------------------
// attn: 512 threads (8 waves, 256 Q-rows), 256 blocks = 1/CU.
// Quad-buffered 32-L tiles, prefetch distance 3, raw s_barrier +
// s_waitcnt vmcnt(4): newest batch stays in flight across every barrier.
// Cross-iteration S pipeline: QK^T MFMAs for tile it+1 are interleaved
// with softmax+PV of tile it, so the wave never stalls on its own S.
// K tiles are XOR-swizzled (source-side, LDS linear — rule #21):
// global chunk g = s ^ (row&15) -> conflict-free ds_read_b128.
// ---------------------------------------------------------------------------
__global__ __launch_bounds__(512, 2) void attn_kernel(
    const float* __restrict__ Q, const float* __restrict__ t1,
    const float* __restrict__ t2pre, const float* __restrict__ ltau,
    const bf16_t* __restrict__ Khi, const bf16_t* __restrict__ Klo,
    const f16_t* __restrict__ Vt, float* __restrict__ out) {
  // per buffer: [K hi 8192 | K lo 8192 | V 10240] = 26624 B
  __shared__ __align__(16) char sBuf[4][26624];
  __shared__ __align__(16) float sT2[1024];

  const int tid = threadIdx.x, lane = tid & 63, wave = tid >> 6;
  const int h = lane >> 5, l31 = lane & 31;
  const int nh = blockIdx.x & 63;                  // head's 4 T-blocks share XCD slot
  const int tB = (blockIdx.x >> 6) << 8;
  const int n = nh >> 3;
  const int qrow = tB + wave * 32 + l31;
  const float negc2 = -__expf(-ltau[0]) * 1.44269504f;

  // 32 chunk slots (26 real + 6 dups), 4 per wave -> uniform vmcnt accounting
  const char* gp[4]; int ls[4]; int st[4];
  for (int a = 0; a < 4; ++a) {
    int j = wave + 8 * a;
    if (j >= 26) j -= 6;                           // dup-stage V chunks 20..25
    if (j < 16) {                                  // K: 16 chunks, swizzled source
      int o = j * 1024 + lane * 16;
      int half = o >> 13;
      int r2 = o & 8191;
      int row = r2 >> 8;
      int s = (r2 >> 4) & 15;
      int g = s ^ (row & 15);                      // XOR-swizzle on GLOBAL side
      gp[a] = (const char*)(half ? Klo : Khi) +
              ((size_t)((nh << 10) + row)) * 256 + (g << 4);
      st[a] = 8192; ls[a] = o;
    } else {                                       // V: 10 chunks, padded 80B rows
      int o = (j - 16) * 1024 + lane * 16;
      int c = o / 80, rem = o % 80;
      if (rem >= 64) rem = 0;
      gp[a] = (const char*)Vt + ((size_t)((nh << 7) + c)) * 2048 + rem;
      st[a] = 64; ls[a] = 16384 + o;
    }
  }
  auto stage = [&](int buf) {
    for (int a = 0; a < 4; ++a) { async_ld16(sBuf[buf] + ls[a], gp[a]); gp[a] += st[a]; }
  };

  // t2 -> LDS (one-time), then Q loads, then prime 3 tile batches
  float2 t2v2 = *(const float2*)(t2pre + (n << 10) + tid * 2);
  const float t1v = t1[(n << 10) + qrow];
  bf16x8 qh[8], ql[8];
  {
    const float* qr = Q + ((size_t)(nh << 10) + qrow) * 128;
    for (int ks = 0; ks < 8; ++ks) {
      const float* p = qr + ks * 16 + h * 8;
      float4 v0 = *(const float4*)p;
      float4 v1 = *(const float4*)(p + 4);
      float vv[8] = {v0.x, v0.y, v0.z, v0.w, v1.x, v1.y, v1.z, v1.w};
      bf16x8 hi, lo;
      for (int j = 0; j < 8; ++j) {
        bf16_t hj = (bf16_t)vv[j];
        hi[j] = hj;
        lo[j] = (bf16_t)(vv[j] - (float)hj);
      }
      qh[ks] = hi;
      ql[ks] = lo;
    }
  }
  stage(0);
  stage(1);
  stage(2);
  *(float2*)(sT2 + tid * 2) = t2v2;

  floatx16 O[4];
  for (int i = 0; i < 4; ++i) O[i] = {};
  float ds = 0.f;

  // gate: stage(0)+stage(1) done (4 newer = stage(2) in flight), t2 written
  asm volatile("s_waitcnt vmcnt(4) lgkmcnt(0)" ::: "memory");
  __builtin_amdgcn_s_barrier();
  asm volatile("" ::: "memory");

  // prologue: S for tile 0 (swizzled K read)
  floatx16 S = {};
  {
    const char* kb = sBuf[0];
#pragma unroll
    for (int ks = 0; ks < 8; ++ks) {
      const int bo = l31 * 256 + ((((ks << 1) + h) ^ (l31 & 15)) << 4);
      bf16x8 kh_ = *(const bf16x8*)(kb + bo);
      bf16x8 kl_ = *(const bf16x8*)(kb + 8192 + bo);
      S = mfma32_bf16(kh_, qh[ks], S);
      S = mfma32_bf16(kl_, qh[ks], S);
      S = mfma32_bf16(kh_, ql[ks], S);
    }
  }

  for (int it = 0; it < 31; ++it) {
    if (it <= 28) stage((it + 3) & 3);
    const char* vb = sBuf[it & 3] + 16384;
    const char* kbn = sBuf[(it + 1) & 3];
    const float* t2b = sT2 + it * 32 + h * 4;
    floatx16 Sn = {};
#pragma unroll
    for (int ks = 0; ks < 8; ++ks) {
      // QK^T for NEXT tile — results unused this iteration, no stall
      {
        const int bo = l31 * 256 + ((((ks << 1) + h) ^ (l31 & 15)) << 4);
        bf16x8 kh_ = *(const bf16x8*)(kbn + bo);
        bf16x8 kl_ = *(const bf16x8*)(kbn + 8192 + bo);
        Sn = mfma32_bf16(kh_, qh[ks], Sn);
        Sn = mfma32_bf16(kl_, qh[ks], Sn);
        Sn = mfma32_bf16(kh_, ql[ks], Sn);
      }
      // softmax + PV for CURRENT tile, interleaved per ks-pair
      if (ks & 1) {
        const int t = ks >> 1;
        float4 tv4 = *(const float4*)(t2b + t * 8);
        float tv[4] = {tv4.x, tv4.y, tv4.z, tv4.w};
        f16x4 pb;
        for (int j = 0; j < 4; ++j) {
          float s = S[4 * t + j];
          float e = fast_exp2(s * s * negc2);
          bool m = (t1v >= tv[j]);
          ds += m ? e : 1.f;
          pb[j] = (f16_t)(m ? e : 0.f);
        }
        for (int ct = 0; ct < 4; ++ct) {
          f16x4 va = *(const f16x4*)(vb + (ct * 32 + l31) * 80 + t * 16 + h * 8);
          O[ct] = mfma32x8_f16(va, pb, O[ct]);
        }
      }
    }
    S = Sn;

    // retire the batch the NEXT iteration reads; newest stays in flight
    if (it <= 28) {
      asm volatile("s_waitcnt vmcnt(4)" ::: "memory");
    } else if (it == 29) {
      asm volatile("s_waitcnt vmcnt(0)" ::: "memory");
    }
    asm volatile("" ::: "memory");
    __builtin_amdgcn_s_barrier();
    asm volatile("" ::: "memory");
  }

  // tail: softmax + PV for tile 31 (S already computed in iter 30)
  {
    const char* vb = sBuf[3] + 16384;
    const float* t2b = sT2 + 31 * 32 + h * 4;
#pragma unroll
    for (int t = 0; t < 4; ++t) {
      float4 tv4 = *(const float4*)(t2b + t * 8);
      float tv[4] = {tv4.x, tv4.y, tv4.z, tv4.w};
      f16x4 pb;
      for (int j = 0; j < 4; ++j) {
        float s = S[4 * t + j];
        float e = fast_exp2(s * s * negc2);
        bool m = (t1v >= tv[j]);
        ds += m ? e : 1.f;
        pb[j] = (f16_t)(m ? e : 0.f);
      }
      for (int ct = 0; ct < 4; ++ct) {
        f16x4 va = *(const f16x4*)(vb + (ct * 32 + l31) * 80 + t * 16 + h * 8);
        O[ct] = mfma32x8_f16(va, pb, O[ct]);
      }
    }
  }

  ds += __shfl_xor(ds, 32);
  const float inv = 1.f / ds;
  float* orow = out + ((size_t)(nh << 10) + qrow) * 128;
  for (int ct = 0; ct < 4; ++ct)
    for (int t = 0; t < 4; ++t) {
      int c = ct * 32 + 8 * t + 4 * h;
      float4 v = {O[ct][4 * t + 0] * inv, O[ct][4 * t + 1] * inv,
                  O[ct][4 * t + 2] * inv, O[ct][4 * t + 3] * inv};
      *(float4*)(orow + c) = v;
    }
}

extern "C" void kernel_launch(void* const* d_in, const int* in_sizes, int n_in,
                              void* d_out, int out_size, void* d_ws, size_t ws_size,
                              hipStream_t stream) {
  const float* X   = (const float*)d_in[0];
  const float* t1  = (const float*)d_in[1];
  const float* Q   = (const float*)d_in[2];
  const float* Wk1 = (const float*)d_in[3];
  const float* bk1 = (const float*)d_in[4];
  const float* Wk2 = (const float*)d_in[5];
  const float* bk2 = (const float*)d_in[6];
  const float* Wv1 = (const float*)d_in[7];
  const float* bv1 = (const float*)d_in[8];
  const float* Wv2 = (const float*)d_in[9];
  const float* bv2 = (const float*)d_in[10];
  const float* log_tau = (const float*)d_in[11];
  float* out = (float*)d_out;

  const size_t E = (size_t)64 * 1024 * 128;
  bf16_t* Khi = (bf16_t*)d_ws;
  bf16_t* Klo = Khi + E;
  f16_t*  Vt  = (f16_t*)(Klo + E);
  bf16_t* W1p = (bf16_t*)((char*)d_ws + 3 * E * 2);
  bf16_t* W2p = W1p + 32768;
  f16_t*  W3f = (f16_t*)(W2p + 32768);
  f16_t*  W4f = W3f + 16384;
  float*  t2pre = (float*)(W4f + 16384);

  prep_kernel<<<48, 256, 0, stream>>>(Wk1, Wk2, Wv1, Wv2, X, W1p, W2p, W3f, W4f, t2pre);
  mlp_k_kernel<<<1024, 256, 0, stream>>>(X, bk1, bk2, W1p, W2p, Khi, Klo);
  mlp_v_kernel<<<1024, 256, 0, stream>>>(X, bv1, bv2, W3f, W4f, Vt);
  attn_kernel<<<256, 512, 0, stream>>>(Q, t1, t2pre, log_tau, Khi, Klo, Vt, out);
}

// Round 3
// 230.333 us; speedup vs baseline: 1.0110x; 1.0110x over previous
//
#include <hip/hip_runtime.h>
#include <hip/hip_bf16.h>

typedef __bf16 bf16_t;
typedef _Float16 f16_t;
typedef bf16_t bf16x8 __attribute__((ext_vector_type(8)));
typedef f16_t  f16x8  __attribute__((ext_vector_type(8)));
typedef f16_t  f16x4  __attribute__((ext_vector_type(4)));
typedef float  floatx4 __attribute__((ext_vector_type(4)));
typedef float  floatx16 __attribute__((ext_vector_type(16)));
typedef bf16x8 bf16x8u __attribute__((aligned(8)));
typedef f16x8  f16x8u  __attribute__((aligned(8)));

#define DEV static __device__ __forceinline__

DEV floatx4 mfma16_bf16(bf16x8 a, bf16x8 b, floatx4 c) {
  return __builtin_amdgcn_mfma_f32_16x16x32_bf16(a, b, c, 0, 0, 0);
}
DEV floatx4 mfma16_f16(f16x8 a, f16x8 b, floatx4 c) {
  return __builtin_amdgcn_mfma_f32_16x16x32_f16(a, b, c, 0, 0, 0);
}
DEV floatx16 mfma32_bf16(bf16x8 a, bf16x8 b, floatx16 c) {
  return __builtin_amdgcn_mfma_f32_32x32x16_bf16(a, b, c, 0, 0, 0);
}
DEV floatx16 mfma32x8_f16(f16x4 a, f16x4 b, floatx16 c) {
  return __builtin_amdgcn_mfma_f32_32x32x8f16(a, b, c, 0, 0, 0);
}
DEV void async_ld16(void* lds, const void* g) {
  __builtin_amdgcn_global_load_lds(
      (const __attribute__((address_space(1))) unsigned int*)g,
      (__attribute__((address_space(3))) unsigned int*)lds, 16, 0, 0);
}
DEV float fast_exp2(float x) {  // v_exp_f32 = 2^x, no libm slow path
  float r;
  asm("v_exp_f32 %0, %1" : "=v"(r) : "v"(x));
  return r;
}

// ---------------------------------------------------------------------------
// Prep: LDS-transposed weight prep (coalesced stores). K weights -> bf16 hi/lo
// [n][k] (+lo at +16384 elems); V weights -> f16 [n][k]. Plus t2 gather.
// ---------------------------------------------------------------------------
__global__ void prep_kernel(const float* __restrict__ Wk1, const float* __restrict__ Wk2,
                            const float* __restrict__ Wv1, const float* __restrict__ Wv2,
                            const float* __restrict__ X,
                            bf16_t* __restrict__ W1p, bf16_t* __restrict__ W2p,
                            f16_t* __restrict__ W3f, f16_t* __restrict__ W4f,
                            float* __restrict__ t2pre) {
  int b = blockIdx.x;
  if (b < 16) {
    int m = b >> 2, p = b & 3;   // weight m, k-quarter p (rows k in [32p,32p+32))
    const float* src = m == 0 ? Wk1 : m == 1 ? Wk2 : m == 2 ? Wv1 : Wv2;
    __shared__ float tile[32][129];
    for (int u = 0; u < 4; ++u) {
      int idx = threadIdx.x + u * 256;        // 1024 float4 units
      int k = idx >> 5, n4 = (idx & 31) << 2;
      float4 v = *(const float4*)(src + (size_t)(p * 32 + k) * 128 + n4);
      tile[k][n4 + 0] = v.x; tile[k][n4 + 1] = v.y;
      tile[k][n4 + 2] = v.z; tile[k][n4 + 3] = v.w;
    }
    __syncthreads();
    if (m < 2) {
      bf16_t* dst = m ? W2p : W1p;
      for (int u = 0; u < 2; ++u) {
        int idx = threadIdx.x + u * 256;      // 512 units: n, k-chunk of 8
        int n = idx >> 2, kc = idx & 3;
        bf16x8 hi, lo;
        for (int j = 0; j < 8; ++j) {
          float v = tile[kc * 8 + j][n];
          bf16_t hh = (bf16_t)v;
          hi[j] = hh;
          lo[j] = (bf16_t)(v - (float)hh);
        }
        *(bf16x8*)(dst + n * 128 + p * 32 + kc * 8) = hi;
        *(bf16x8*)(dst + 16384 + n * 128 + p * 32 + kc * 8) = lo;
      }
    } else {
      f16_t* dst = (m == 3) ? W4f : W3f;
      for (int u = 0; u < 2; ++u) {
        int idx = threadIdx.x + u * 256;
        int n = idx >> 2, kc = idx & 3;
        f16x8 w;
        for (int j = 0; j < 8; ++j) w[j] = (f16_t)tile[kc * 8 + j][n];
        *(f16x8*)(dst + n * 128 + p * 32 + kc * 8) = w;
      }
    }
  } else {
    int i = (b - 16) * 256 + threadIdx.x;     // n*1024 + l
    t2pre[i] = X[((size_t)(i >> 10) * 8192 + (i & 1023)) * 128 + 127];
  }
}

// ---------------------------------------------------------------------------
// MLP-K: split-bf16, 64 rows/block, dbuf weight staging (8 phases).
// ---------------------------------------------------------------------------
__global__ __launch_bounds__(256) void mlp_k_kernel(
    const float* __restrict__ X, const float* __restrict__ b1,
    const float* __restrict__ b2, const bf16_t* __restrict__ W1p,
    const bf16_t* __restrict__ W2p, bf16_t* __restrict__ Khi,
    bf16_t* __restrict__ Klo) {
  __shared__ __align__(16) char sXbuf[2 * 16896];
  __shared__ __align__(16) bf16_t sW[2][256 * 40];
  bf16_t* sXh = (bf16_t*)sXbuf;
  bf16_t* sXl = sXh + 64 * 132;

  const int tid = threadIdx.x, lane = tid & 63, wave = tid >> 6;
  const int q = lane >> 4, c15 = lane & 15;
  const size_t rowBase = (size_t)blockIdx.x * 64;

  int goff[5];
  for (int a = 0; a < 5; ++a) {
    int o = (wave + 4 * a) * 1024 + lane * 16;
    int row = o / 80, rem = o % 80;
    goff[a] = row * 256 + (rem < 64 ? rem : 0);
  }
  auto issueW = [&](int buf, int ph) {
    const bf16_t* Wp = (ph < 4) ? W1p : W2p;
    const char* base = (const char*)Wp + (ph & 3) * 64;
    for (int a = 0; a < 5; ++a)
      async_ld16((char*)sW[buf] + (wave + 4 * a) * 1024 + lane * 16, base + goff[a]);
  };

  issueW(0, 0);    // prefetch W phase 0 under X conversion

  float b1v[8], b2v[8];
  for (int nt = 0; nt < 8; ++nt) { b1v[nt] = b1[nt * 16 + c15]; b2v[nt] = b2[nt * 16 + c15]; }

  for (int u = 0; u < 8; ++u) {
    int idx = tid + u * 256;
    int r = idx >> 5, c4 = (idx & 31) << 2;
    float4 v = *(const float4*)(X + (rowBase + r) * 128 + c4);
    int o = r * 132 + c4;
    float vv[4] = {v.x, v.y, v.z, v.w};
    for (int i = 0; i < 4; ++i) {
      bf16_t h = (bf16_t)vv[i];
      sXh[o + i] = h;
      sXl[o + i] = (bf16_t)(vv[i] - (float)h);
    }
  }

  floatx4 acc1[8], acc2[8];
  for (int i = 0; i < 8; ++i) { acc1[i] = {}; acc2[i] = {}; }

  __syncthreads();
#pragma unroll
  for (int ph = 0; ph < 8; ++ph) {
    if (ph < 7) issueW((ph + 1) & 1, ph + 1);
    const bf16_t* wb = sW[ph & 1];
    const int kq = ph & 3;
    floatx4* acc = (ph < 4) ? acc1 : acc2;
    const int ao = (wave * 16 + c15) * 132 + kq * 32 + q * 8;
    bf16x8 ah = *(const bf16x8u*)(sXh + ao);
    bf16x8 al = *(const bf16x8u*)(sXl + ao);
    for (int nt = 0; nt < 8; ++nt) {
      const int bo = (nt * 16 + c15) * 40 + q * 8;
      bf16x8 bh = *(const bf16x8*)(wb + bo);
      bf16x8 bl = *(const bf16x8*)(wb + 128 * 40 + bo);
      acc[nt] = mfma16_bf16(ah, bh, acc[nt]);
      acc[nt] = mfma16_bf16(ah, bl, acc[nt]);
      acc[nt] = mfma16_bf16(al, bh, acc[nt]);
    }
    if (ph == 3) {
      for (int nt = 0; nt < 8; ++nt)
        for (int r = 0; r < 4; ++r) {
          float h = fmaxf(acc1[nt][r] + b1v[nt], 0.f);
          bf16_t hh = (bf16_t)h;
          int o = (wave * 16 + q * 4 + r) * 132 + nt * 16 + c15;
          sXh[o] = hh;
          sXl[o] = (bf16_t)(h - (float)hh);
        }
    }
    __syncthreads();
  }

  for (int nt = 0; nt < 8; ++nt)
    for (int r = 0; r < 4; ++r) {
      float kv = acc2[nt][r] + b2v[nt];
      bf16_t kh = (bf16_t)kv;
      int o = (wave * 16 + q * 4 + r) * 132 + nt * 16 + c15;
      sXh[o] = kh;
      sXl[o] = (bf16_t)(kv - (float)kh);
    }
  __syncthreads();
  for (int u = 0; u < 4; ++u) {
    int idx = tid + u * 256;
    int r = idx >> 4, c8 = (idx & 15) << 3;
    bf16x8 vh = *(const bf16x8u*)(sXh + r * 132 + c8);
    bf16x8 vl = *(const bf16x8u*)(sXl + r * 132 + c8);
    *(bf16x8*)(Khi + (rowBase + r) * 128 + c8) = vh;
    *(bf16x8*)(Klo + (rowBase + r) * 128 + c8) = vl;
  }
}

// ---------------------------------------------------------------------------
// MLP-V: pure f16 (R2-proven numerics), dbuf phases; emits V^T (f16).
// ---------------------------------------------------------------------------
__global__ __launch_bounds__(256) void mlp_v_kernel(
    const float* __restrict__ X, const float* __restrict__ b1,
    const float* __restrict__ b2, const f16_t* __restrict__ W1f,
    const f16_t* __restrict__ W2f, f16_t* __restrict__ Vt) {
  __shared__ __align__(16) f16_t sXf[64 * 136];    // X/H; later V^T [128][68]
  __shared__ __align__(16) f16_t sW[2][128 * 40];

  const int tid = threadIdx.x, lane = tid & 63, wave = tid >> 6;
  const int q = lane >> 4, c15 = lane & 15;
  const size_t rowBase = (size_t)blockIdx.x * 64;

  int goff[3];
  for (int a = 0; a < 3; ++a) {
    int o = (wave + 4 * a) * 1024 + lane * 16;
    int row = o / 80, rem = o % 80;
    goff[a] = row * 256 + (rem < 64 ? rem : 0);
  }
  auto issueV = [&](int buf, int ph) {
    const f16_t* Wp = (ph < 4) ? W1f : W2f;
    const char* base = (const char*)Wp + (ph & 3) * 64;
    for (int a = 0; a < 3; ++a) {
      int j = wave + 4 * a;
      if (j < 10) async_ld16((char*)sW[buf] + j * 1024 + lane * 16, base + goff[a]);
    }
  };

  issueV(0, 0);

  float b1v[8], bvv[2][4];
  for (int nt = 0; nt < 8; ++nt) b1v[nt] = b1[nt * 16 + c15];
  for (int mt = 0; mt < 2; ++mt)
    for (int r = 0; r < 4; ++r)
      bvv[mt][r] = b2[(wave * 2 + mt) * 16 + q * 4 + r];

  for (int u = 0; u < 8; ++u) {
    int idx = tid + u * 256;
    int r = idx >> 5, c4 = (idx & 31) << 2;
    float4 v = *(const float4*)(X + (rowBase + r) * 128 + c4);
    int o = r * 136 + c4;
    sXf[o + 0] = (f16_t)v.x; sXf[o + 1] = (f16_t)v.y;
    sXf[o + 2] = (f16_t)v.z; sXf[o + 3] = (f16_t)v.w;
  }

  floatx4 acc1[8], acc2[2][4];
  for (int i = 0; i < 8; ++i) acc1[i] = {};
  for (int i = 0; i < 2; ++i) for (int j = 0; j < 4; ++j) acc2[i][j] = {};

  __syncthreads();
#pragma unroll
  for (int ph = 0; ph < 8; ++ph) {
    if (ph < 7) issueV((ph + 1) & 1, ph + 1);
    const f16_t* wb = sW[ph & 1];
    const int kq = ph & 3;
    if (ph < 4) {
      f16x8 a = *(const f16x8u*)(sXf + (wave * 16 + c15) * 136 + kq * 32 + q * 8);
      for (int nt = 0; nt < 8; ++nt) {
        f16x8 bb = *(const f16x8*)(wb + (nt * 16 + c15) * 40 + q * 8);
        acc1[nt] = mfma16_f16(a, bb, acc1[nt]);
      }
      if (ph == 3) {
        for (int nt = 0; nt < 8; ++nt)
          for (int r = 0; r < 4; ++r)
            sXf[(wave * 16 + q * 4 + r) * 136 + nt * 16 + c15] =
                (f16_t)fmaxf(acc1[nt][r] + b1v[nt], 0.f);
      }
    } else {
      f16x8 aw0 = *(const f16x8*)(wb + ((wave * 2 + 0) * 16 + c15) * 40 + q * 8);
      f16x8 aw1 = *(const f16x8*)(wb + ((wave * 2 + 1) * 16 + c15) * 40 + q * 8);
      for (int nt = 0; nt < 4; ++nt) {
        f16x8 bh = *(const f16x8u*)(sXf + (nt * 16 + c15) * 136 + kq * 32 + q * 8);
        acc2[0][nt] = mfma16_f16(aw0, bh, acc2[0][nt]);
        acc2[1][nt] = mfma16_f16(aw1, bh, acc2[1][nt]);
      }
    }
    __syncthreads();
  }

  f16_t* sVT = sXf;   // [128][68] f16
  for (int mt = 0; mt < 2; ++mt)
    for (int nt = 0; nt < 4; ++nt)
      for (int r = 0; r < 4; ++r) {
        int c = (wave * 2 + mt) * 16 + q * 4 + r;
        sVT[c * 68 + nt * 16 + c15] = (f16_t)(acc2[mt][nt][r] + bvv[mt][r]);
      }
  __syncthreads();
  const int nh = (int)(rowBase >> 10);
  const int lB = (int)(rowBase & 1023);
  for (int u = 0; u < 4; ++u) {
    int idx = tid + u * 256;
    int c = idx >> 3, l8 = (idx & 7) << 3;
    *(f16x8*)(Vt + ((size_t)nh * 128 + c) * 1024 + lB + l8) =
        *(const f16x8u*)(sVT + c * 68 + l8);
  }
}

// ---------------------------------------------------------------------------
// attn: 256 threads (4 waves, 128 Q-rows), 512 blocks = 2/CU. Two independent
// blocks per CU at free-running phases fill each other's MFMA/VALU/LDS stalls
// (registers forbid >2 waves/SIMD; TLP must come from block-level desync).
// Triple-buffered 32-L tiles, distance-2 prefetch, counted vmcnt(6) (6 uniform
// chunks/wave/batch, no dups). K source-XOR-swizzle as before; V re-packed to
// 64B rows with 16B-unit XOR swizzle (global-side pre-permute within one 64B
// line) -> b64 reads run at the 4-cycle floor, tile shrinks 10240->8192 so
// LDS = 3*24576+4096 = 77824 <= 80KB -> 2 blocks/CU. setprio(1) around the
// S-MFMA cluster (T5; phase diversity now exists across blocks).
// ---------------------------------------------------------------------------
__global__ __launch_bounds__(256, 2) void attn_kernel(
    const float* __restrict__ Q, const float* __restrict__ t1,
    const float* __restrict__ t2pre, const float* __restrict__ ltau,
    const bf16_t* __restrict__ Khi, const bf16_t* __restrict__ Klo,
    const f16_t* __restrict__ Vt, float* __restrict__ out) {
  // per buffer: [K hi 8192 | K lo 8192 | V 8192] = 24576 B
  __shared__ __align__(16) char sBuf[3][24576];
  __shared__ __align__(16) float sT2[1024];

  const int tid = threadIdx.x, lane = tid & 63, wave = tid >> 6;
  const int h = lane >> 5, l31 = lane & 31;
  const int nh = blockIdx.x & 63;                  // same-head blocks share XCD slot
  const int seg = blockIdx.x >> 6;                 // 0..7: 128-row segment
  const int n = nh >> 3;
  const int qrow = seg * 128 + wave * 32 + l31;
  const float negc2 = -__expf(-ltau[0]) * 1.44269504f;
  const int vswz = (l31 >> 1) & 3;

  // 24 chunks: 16 K + 8 V, 6 per wave -> uniform vmcnt accounting, no dups
  const char* gp[6]; int ls[6]; int st[6];
  for (int a = 0; a < 6; ++a) {
    int j = wave + 4 * a;
    if (j < 16) {                                  // K: swizzled global source
      int o = j * 1024 + lane * 16;
      int half = o >> 13;
      int r2 = o & 8191;
      int row = r2 >> 8;
      int s = (r2 >> 4) & 15;
      int g = s ^ (row & 15);                      // XOR-swizzle on GLOBAL side
      gp[a] = (const char*)(half ? Klo : Khi) +
              ((size_t)((nh << 10) + row)) * 256 + (g << 4);
      st[a] = 8192; ls[a] = o;
    } else {                                       // V: 64B rows, unit-XOR swizzle
      int o = (j - 16) * 1024 + lane * 16;         // 0..8191
      int c = o >> 6;                              // V^T row (column of V)
      int u = (o >> 4) & 3;                        // 16B unit within row
      int up = u ^ ((c >> 1) & 3);                 // pre-permute global source
      gp[a] = (const char*)Vt + ((size_t)((nh << 7) + c)) * 2048 + up * 16;
      st[a] = 64; ls[a] = 16384 + o;
    }
  }
  auto stage = [&](int buf) {
    for (int a = 0; a < 6; ++a) { async_ld16(sBuf[buf] + ls[a], gp[a]); gp[a] += st[a]; }
  };

  // t2 -> LDS (one-time), Q loads, prime 2 tile batches
  float4 t2v4 = *(const float4*)(t2pre + (n << 10) + tid * 4);
  const float t1v = t1[(n << 10) + qrow];
  bf16x8 qh[8], ql[8];
  {
    const float* qr = Q + ((size_t)(nh << 10) + qrow) * 128;
    for (int ks = 0; ks < 8; ++ks) {
      const float* p = qr + ks * 16 + h * 8;
      float4 v0 = *(const float4*)p;
      float4 v1 = *(const float4*)(p + 4);
      float vv[8] = {v0.x, v0.y, v0.z, v0.w, v1.x, v1.y, v1.z, v1.w};
      bf16x8 hi, lo;
      for (int j = 0; j < 8; ++j) {
        bf16_t hj = (bf16_t)vv[j];
        hi[j] = hj;
        lo[j] = (bf16_t)(vv[j] - (float)hj);
      }
      qh[ks] = hi;
      ql[ks] = lo;
    }
  }
  stage(0);
  stage(1);
  *(float4*)(sT2 + tid * 4) = t2v4;

  floatx16 O[4];
  for (int i = 0; i < 4; ++i) O[i] = {};
  float ds = 0.f;

  // gate: batch 0 done (6 newer = batch 1 in flight), t2 ds_write done
  asm volatile("s_waitcnt vmcnt(6) lgkmcnt(0)" ::: "memory");
  __builtin_amdgcn_s_barrier();
  asm volatile("" ::: "memory");

  for (int it = 0; it < 32; ++it) {
    if (it <= 29) stage((it + 2) % 3);
    const char* kb = sBuf[it % 3];
    const char* vb = kb + 16384;

    floatx16 S = {};
    __builtin_amdgcn_s_setprio(1);
#pragma unroll
    for (int ks = 0; ks < 8; ++ks) {
      const int bo = l31 * 256 + ((((ks << 1) + h) ^ (l31 & 15)) << 4);
      bf16x8 kh_ = *(const bf16x8*)(kb + bo);
      bf16x8 kl_ = *(const bf16x8*)(kb + 8192 + bo);
      S = mfma32_bf16(kh_, qh[ks], S);
      S = mfma32_bf16(kl_, qh[ks], S);
      S = mfma32_bf16(kh_, ql[ks], S);
    }
    __builtin_amdgcn_s_setprio(0);

    const float* t2b = sT2 + it * 32 + h * 4;
    for (int t = 0; t < 4; ++t) {
      float4 tv4 = *(const float4*)(t2b + t * 8);
      float tv[4] = {tv4.x, tv4.y, tv4.z, tv4.w};
      f16x4 pb;
      for (int j = 0; j < 4; ++j) {
        float s = S[4 * t + j];
        float e = fast_exp2(s * s * negc2);
        bool m = (t1v >= tv[j]);
        ds += m ? e : 1.f;
        pb[j] = (f16_t)(m ? e : 0.f);
      }
      for (int ct = 0; ct < 4; ++ct) {
        f16x4 va = *(const f16x4*)(vb + (ct * 32 + l31) * 64 +
                                   ((t ^ vswz) << 4) + h * 8);
        O[ct] = mfma32x8_f16(va, pb, O[ct]);
      }
    }

    // retire the batch the NEXT iteration reads; newest stays in flight
    if (it <= 29) {
      asm volatile("s_waitcnt vmcnt(6)" ::: "memory");
    } else if (it == 30) {
      asm volatile("s_waitcnt vmcnt(0)" ::: "memory");
    }
    if (it < 31) {
      asm volatile("" ::: "memory");
      __builtin_amdgcn_s_barrier();
      asm volatile("" ::: "memory");
    }
  }

  ds += __shfl_xor(ds, 32);
  const float inv = 1.f / ds;
  float* orow = out + ((size_t)(nh << 10) + qrow) * 128;
  for (int ct = 0; ct < 4; ++ct)
    for (int t = 0; t < 4; ++t) {
      int c = ct * 32 + 8 * t + 4 * h;
      float4 v = {O[ct][4 * t + 0] * inv, O[ct][4 * t + 1] * inv,
                  O[ct][4 * t + 2] * inv, O[ct][4 * t + 3] * inv};
      *(float4*)(orow + c) = v;
    }
}

extern "C" void kernel_launch(void* const* d_in, const int* in_sizes, int n_in,
                              void* d_out, int out_size, void* d_ws, size_t ws_size,
                              hipStream_t stream) {
  const float* X   = (const float*)d_in[0];
  const float* t1  = (const float*)d_in[1];
  const float* Q   = (const float*)d_in[2];
  const float* Wk1 = (const float*)d_in[3];
  const float* bk1 = (const float*)d_in[4];
  const float* Wk2 = (const float*)d_in[5];
  const float* bk2 = (const float*)d_in[6];
  const float* Wv1 = (const float*)d_in[7];
  const float* bv1 = (const float*)d_in[8];
  const float* Wv2 = (const float*)d_in[9];
  const float* bv2 = (const float*)d_in[10];
  const float* log_tau = (const float*)d_in[11];
  float* out = (float*)d_out;

  const size_t E = (size_t)64 * 1024 * 128;
  bf16_t* Khi = (bf16_t*)d_ws;
  bf16_t* Klo = Khi + E;
  f16_t*  Vt  = (f16_t*)(Klo + E);
  bf16_t* W1p = (bf16_t*)((char*)d_ws + 3 * E * 2);
  bf16_t* W2p = W1p + 32768;
  f16_t*  W3f = (f16_t*)(W2p + 32768);
  f16_t*  W4f = W3f + 16384;
  float*  t2pre = (float*)(W4f + 16384);

  prep_kernel<<<48, 256, 0, stream>>>(Wk1, Wk2, Wv1, Wv2, X, W1p, W2p, W3f, W4f, t2pre);
  mlp_k_kernel<<<1024, 256, 0, stream>>>(X, bk1, bk2, W1p, W2p, Khi, Klo);
  mlp_v_kernel<<<1024, 256, 0, stream>>>(X, bv1, bv2, W3f, W4f, Vt);
  attn_kernel<<<512, 256, 0, stream>>>(Q, t1, t2pre, log_tau, Khi, Klo, Vt, out);
}